// Round 3
// baseline (28068.481 us; speedup 1.0000x reference)
//
#include <hip/hip_runtime.h>
#include <hip/hip_bf16.h>

#define B_ 8
#define S_ 4096
#define F_ 256
#define I_ 512
#define D_ 4
#define K_ 7
#define V_ 256
#define I3_ 1536

using bf16 = __hip_bfloat16;

__device__ __forceinline__ float mishf(float x) {
    float sp = fmaxf(x, 0.0f) + log1pf(expf(-fabsf(x)));
    return x * tanhf(sp);
}

__device__ __forceinline__ float loadw(const void* p, size_t i, int isbf) {
    return isbf ? __bfloat162float(((const bf16*)p)[i]) : ((const float*)p)[i];
}

// bf16 buffers of small weights never show bf16-exponent>=132 (|x|>=32);
// fp32 buffers read as uint16 do (~half of the low-half words).
__global__ __launch_bounds__(256)
void detect_kernel(int* __restrict__ flag, const unsigned short* __restrict__ p)
{
    __shared__ int sh[256];
    int cnt = 0;
    for (int j = threadIdx.x; j < 16384; j += 256) {
        unsigned int e = (p[j] >> 7) & 0xffu;
        if (e >= 132u) cnt++;
    }
    sh[threadIdx.x] = cnt;
    __syncthreads();
    for (int s = 128; s > 0; s >>= 1) {
        if ((int)threadIdx.x < s) sh[threadIdx.x] += sh[threadIdx.x + s];
        __syncthreads();
    }
    if (threadIdx.x == 0) flag[0] = (sh[0] == 0) ? 1 : 0;   // 1 => bf16 inputs
}

__global__ __launch_bounds__(256)
void embed_kernel(float* __restrict__ x0, float* __restrict__ x1,
                  const int* __restrict__ inp, const void* __restrict__ emb,
                  const int* __restrict__ flag)
{
    const int isbf = flag[0];
    size_t idx = (size_t)blockIdx.x * 256 + threadIdx.x;   // over B*F*S
    int s = (int)(idx % S_);
    int f = (int)((idx / S_) % F_);
    int b = (int)(idx / ((size_t)S_ * F_));
    int tok = inp[b * S_ + s];
    x0[idx] = loadw(emb, (size_t)tok * (2 * F_) + f, isbf);
    x1[idx] = loadw(emb, (size_t)tok * (2 * F_) + F_ + f, isbf);
}

// out[o,s] (+)= sum_c w[woff + o*C + c] * x[c,s]; 64x64 tile, 4x4/thread
__global__ __launch_bounds__(256)
void conv1x1_kernel(float* __restrict__ out, const float* __restrict__ x,
                    const void* __restrict__ w, size_t woff, int O, int C,
                    int addres, const int* __restrict__ flag)
{
    __shared__ float wl[16][68];
    __shared__ float xl[16][68];
    const int isbf = flag[0];
    const int tid = threadIdx.x;
    const int tx = tid & 15, ty = tid >> 4;
    const int s0 = blockIdx.x * 64;
    const int o0 = blockIdx.y * 64;
    float acc[4][4] = {};
    for (int c0 = 0; c0 < C; c0 += 16) {
        if (isbf) {
            #pragma unroll
            for (int e = tid; e < 1024; e += 256) {
                int k = e & 15, o = e >> 4;
                wl[k][o] = __bfloat162float(((const bf16*)w)[woff + (size_t)(o0 + o) * C + (c0 + k)]);
            }
        } else {
            #pragma unroll
            for (int e = tid; e < 1024; e += 256) {
                int k = e & 15, o = e >> 4;
                wl[k][o] = ((const float*)w)[woff + (size_t)(o0 + o) * C + (c0 + k)];
            }
        }
        {
            int r = tid >> 4;
            int q = (tid & 15) * 4;
            *(float4*)&xl[r][q] = *(const float4*)(x + (size_t)(c0 + r) * S_ + (s0 + q));
        }
        __syncthreads();
        #pragma unroll
        for (int k = 0; k < 16; ++k) {
            float4 av = *(const float4*)&wl[k][ty * 4];
            float4 bv = *(const float4*)&xl[k][tx * 4];
            #pragma unroll
            for (int i = 0; i < 4; ++i)
                #pragma unroll
                for (int j = 0; j < 4; ++j)
                    acc[i][j] += (&av.x)[i] * (&bv.x)[j];
        }
        __syncthreads();
    }
    #pragma unroll
    for (int i = 0; i < 4; ++i) {
        int o = o0 + ty * 4 + i;
        float* po = out + (size_t)o * S_ + s0 + tx * 4;
        float4 r = make_float4(acc[i][0], acc[i][1], acc[i][2], acc[i][3]);
        if (addres) {
            float4 old = *(const float4*)po;
            r.x += old.x; r.y += old.y; r.z += old.z; r.w += old.w;
        }
        *(float4*)po = r;
    }
}

// v[i,s] = cumsum_s(mish(t[i,s]))/(s+1) * mish(t[I+i,s]) + mish(t[2I+i,s])
__global__ __launch_bounds__(256)
void scan_kernel(float* __restrict__ vout, const float* __restrict__ t)
{
    const int i = blockIdx.x;
    const float* dp  = t + (size_t)i * S_;
    const float* scp = dp + (size_t)I_ * S_;
    const float* shp = dp + (size_t)(2 * I_) * S_;
    float* op = vout + (size_t)i * S_;
    const int tid = threadIdx.x;
    const int base = tid * 16;

    float md[16];
    float lsum = 0.f;
    #pragma unroll
    for (int q = 0; q < 4; ++q) {
        float4 dv = *(const float4*)(dp + base + q * 4);
        #pragma unroll
        for (int j = 0; j < 4; ++j) {
            float m = mishf((&dv.x)[j]);
            md[q * 4 + j] = m;
            lsum += m;
        }
    }
    float ssum = lsum;
    #pragma unroll
    for (int off = 1; off < 64; off <<= 1) {
        float nv = __shfl_up(ssum, off, 64);
        if ((tid & 63) >= off) ssum += nv;
    }
    __shared__ float wtot[4];
    const int wid = tid >> 6, lane = tid & 63;
    if (lane == 63) wtot[wid] = ssum;
    __syncthreads();
    float excl = ssum - lsum;
    #pragma unroll
    for (int wq = 0; wq < 3; ++wq)
        if (wq < wid) excl += wtot[wq];

    float run = excl;
    #pragma unroll
    for (int q = 0; q < 4; ++q) {
        float4 scv = *(const float4*)(scp + base + q * 4);
        float4 shv = *(const float4*)(shp + base + q * 4);
        float4 ov;
        #pragma unroll
        for (int j = 0; j < 4; ++j) {
            run += md[q * 4 + j];
            float sdiv = (float)(base + q * 4 + j + 1);
            (&ov.x)[j] = run / sdiv * mishf((&scv.x)[j]) + mishf((&shv.x)[j]);
        }
        *(float4*)(op + base + q * 4) = ov;
    }
}

// out[o,s] = sum_{c,k} w[woff + o*I*K + c*K + k] * v[c,s-6+k]
__global__ __launch_bounds__(256)
void cconv_kernel(float* __restrict__ out, const float* __restrict__ v,
                  const void* __restrict__ w, size_t woff,
                  const int* __restrict__ flag)
{
    __shared__ float wl[112][68];
    __shared__ float vl[16][72];
    const int isbf = flag[0];
    const int tid = threadIdx.x;
    const int tx = tid & 15, ty = tid >> 4;
    const int s0 = blockIdx.x * 64;
    const int o0 = blockIdx.y * 64;
    float acc[4][4] = {};
    for (int c0 = 0; c0 < I_; c0 += 16) {
        if (isbf) {
            for (int e = tid; e < 112 * 64; e += 256) {
                int q = e % 112, o = e / 112;
                wl[q][o] = __bfloat162float(((const bf16*)w)[woff + (size_t)(o0 + o) * (I_ * K_) + (size_t)c0 * K_ + q]);
            }
        } else {
            for (int e = tid; e < 112 * 64; e += 256) {
                int q = e % 112, o = e / 112;
                wl[q][o] = ((const float*)w)[woff + (size_t)(o0 + o) * (I_ * K_) + (size_t)c0 * K_ + q];
            }
        }
        for (int e = tid; e < 16 * 70; e += 256) {
            int r = e / 70, q = e % 70;
            int si = s0 - 6 + q;
            vl[r][q] = (si >= 0) ? v[(size_t)(c0 + r) * S_ + si] : 0.f;
        }
        __syncthreads();
        for (int cc = 0; cc < 16; ++cc) {
            float win[12];
            *(float4*)&win[0] = *(const float4*)&vl[cc][tx * 4];
            *(float4*)&win[4] = *(const float4*)&vl[cc][tx * 4 + 4];
            *(float4*)&win[8] = *(const float4*)&vl[cc][tx * 4 + 8];
            #pragma unroll
            for (int k = 0; k < 7; ++k) {
                float4 av = *(const float4*)&wl[cc * 7 + k][ty * 4];
                #pragma unroll
                for (int i = 0; i < 4; ++i)
                    #pragma unroll
                    for (int j = 0; j < 4; ++j)
                        acc[i][j] += (&av.x)[i] * win[j + k];
            }
        }
        __syncthreads();
    }
    #pragma unroll
    for (int i = 0; i < 4; ++i) {
        int o = o0 + ty * 4 + i;
        float* po = out + (size_t)o * S_ + s0 + tx * 4;
        *(float4*)po = make_float4(acc[i][0], acc[i][1], acc[i][2], acc[i][3]);
    }
}

__global__ __launch_bounds__(256)
void final_kernel(void* __restrict__ out, const float* __restrict__ x0,
                  const float* __restrict__ x1, const void* __restrict__ ow,
                  const void* __restrict__ ob, const int* __restrict__ flag)
{
    __shared__ float wl[16][68];
    __shared__ float xl[16][68];
    const int isbf = flag[0];
    const int tid = threadIdx.x;
    const int tx = tid & 15, ty = tid >> 4;
    const int s0 = blockIdx.x * 64;
    const int o0 = blockIdx.y * 64;
    const int b  = blockIdx.z;
    float acc[4][4] = {};
    for (int c0 = 0; c0 < 2 * F_; c0 += 16) {
        if (isbf) {
            #pragma unroll
            for (int e = tid; e < 1024; e += 256) {
                int k = e & 15, o = e >> 4;
                wl[k][o] = __bfloat162float(((const bf16*)ow)[(size_t)(o0 + o) * (2 * F_) + (c0 + k)]);
            }
        } else {
            #pragma unroll
            for (int e = tid; e < 1024; e += 256) {
                int k = e & 15, o = e >> 4;
                wl[k][o] = ((const float*)ow)[(size_t)(o0 + o) * (2 * F_) + (c0 + k)];
            }
        }
        {
            int r = tid >> 4;
            int q = (tid & 15) * 4;
            int cr = c0 + r;
            const float* src = (cr < F_) ? (x0 + ((size_t)b * F_ + cr) * S_)
                                         : (x1 + ((size_t)b * F_ + (cr - F_)) * S_);
            *(float4*)&xl[r][q] = *(const float4*)(src + s0 + q);
        }
        __syncthreads();
        #pragma unroll
        for (int k = 0; k < 16; ++k) {
            float4 av = *(const float4*)&wl[k][ty * 4];
            float4 bv = *(const float4*)&xl[k][tx * 4];
            #pragma unroll
            for (int i = 0; i < 4; ++i)
                #pragma unroll
                for (int j = 0; j < 4; ++j)
                    acc[i][j] += (&av.x)[i] * (&bv.x)[j];
        }
        __syncthreads();
    }
    #pragma unroll
    for (int i = 0; i < 4; ++i) {
        int o = o0 + ty * 4 + i;
        float bias = loadw(ob, o, isbf);
        size_t outoff = ((size_t)b * V_ + o) * S_ + s0 + tx * 4;
        if (isbf) {
            bf16* po = (bf16*)out + outoff;
            #pragma unroll
            for (int j = 0; j < 4; ++j)
                po[j] = __float2bfloat16(acc[i][j] + bias);
        } else {
            float* po = (float*)out + outoff;
            *(float4*)po = make_float4(acc[i][0] + bias, acc[i][1] + bias,
                                       acc[i][2] + bias, acc[i][3] + bias);
        }
    }
}

extern "C" void kernel_launch(void* const* d_in, const int* in_sizes, int n_in,
                              void* d_out, int out_size, void* d_ws, size_t ws_size,
                              hipStream_t stream)
{
    const int*  inp  = (const int*)d_in[0];
    const void* emb  = d_in[1];
    const void* w0   = d_in[2];
    const void* w1   = d_in[3];
    const void* w2   = d_in[4];
    const void* outw = d_in[5];
    const void* outb = d_in[6];

    // ws: [flag 256B] + fp32 { A[B,F,S], Bb[B,F,S], T[3I,S], V[I,S] } = 96 MiB
    const size_t NX = (size_t)B_ * F_ * S_;
    const size_t NT = (size_t)I3_ * S_;
    int*   flag = (int*)d_ws;
    float* A  = (float*)d_ws + 64;
    float* Bb = A + NX;
    float* T  = Bb + NX;
    float* Vv = T + NT;

    detect_kernel<<<1, 256, 0, stream>>>(flag, (const unsigned short*)emb);
    embed_kernel<<<dim3((unsigned)(NX / 256)), 256, 0, stream>>>(A, Bb, inp, emb, flag);

    for (int b = 0; b < B_; ++b) {
        float* x0 = A  + (size_t)b * F_ * S_;
        float* x1 = Bb + (size_t)b * F_ * S_;
        for (int d = 0; d < D_; ++d) {
            conv1x1_kernel<<<dim3(S_ / 64, I3_ / 64), 256, 0, stream>>>(
                T, x1, w0, (size_t)d * I3_ * F_, I3_, F_, 0, flag);
            scan_kernel<<<dim3(I_), 256, 0, stream>>>(Vv, T);
            cconv_kernel<<<dim3(S_ / 64, I3_ / 64), 256, 0, stream>>>(
                T, Vv, w1, (size_t)d * I3_ * I_ * K_, flag);
            scan_kernel<<<dim3(I_), 256, 0, stream>>>(Vv, T);
            conv1x1_kernel<<<dim3(S_ / 64, F_ / 64), 256, 0, stream>>>(
                x0, Vv, w2, (size_t)d * F_ * I_, F_, I_, 1, flag);
            float* tmp = x0; x0 = x1; x1 = tmp;
        }
    }
    final_kernel<<<dim3(S_ / 64, V_ / 64, B_), 256, 0, stream>>>(d_out, A, Bb, outw, outb, flag);
    (void)in_sizes; (void)n_in; (void)out_size; (void)ws_size; (void)Vv;
}

// Round 4
// 8743.443 us; speedup vs baseline: 3.2102x; 3.2102x over previous
//
#include <hip/hip_runtime.h>
#include <hip/hip_bf16.h>

#define B_ 8
#define S_ 4096
#define F_ 256
#define I_ 512
#define D_ 4
#define K_ 7
#define V_ 256
#define I3_ 1536

using bf16 = __hip_bfloat16;
typedef __bf16 bf16x8 __attribute__((ext_vector_type(8)));
typedef float  f32x4  __attribute__((ext_vector_type(4)));

__device__ __forceinline__ float mishf(float x) {
    float sp = fmaxf(x, 0.0f) + log1pf(expf(-fabsf(x)));
    return x * tanhf(sp);
}

__device__ __forceinline__ float loadw(const void* p, size_t i, int isbf) {
    return isbf ? __bfloat162float(((const bf16*)p)[i]) : ((const float*)p)[i];
}

// bf16 buffers of small weights never show bf16-exponent>=132 (|x|>=32);
// fp32 buffers read as uint16 do (random mantissa bits in low halves).
__global__ __launch_bounds__(256)
void detect_kernel(int* __restrict__ flag, const unsigned short* __restrict__ p)
{
    __shared__ int sh[256];
    int cnt = 0;
    for (int j = threadIdx.x; j < 16384; j += 256) {
        unsigned int e = (p[j] >> 7) & 0xffu;
        if (e >= 132u) cnt++;
    }
    sh[threadIdx.x] = cnt;
    __syncthreads();
    for (int s = 128; s > 0; s >>= 1) {
        if ((int)threadIdx.x < s) sh[threadIdx.x] += sh[threadIdx.x + s];
        __syncthreads();
    }
    if (threadIdx.x == 0) flag[0] = (sh[0] == 0) ? 1 : 0;   // 1 => bf16 inputs
}

__global__ __launch_bounds__(256)
void embed_kernel(float* __restrict__ x0, float* __restrict__ x1,
                  const int* __restrict__ inp, const void* __restrict__ emb,
                  const int* __restrict__ flag)
{
    const int isbf = flag[0];
    size_t idx = (size_t)blockIdx.x * 256 + threadIdx.x;   // over B*F*S
    int s = (int)(idx % S_);
    int f = (int)((idx / S_) % F_);
    int b = (int)(idx / ((size_t)S_ * F_));
    int tok = inp[b * S_ + s];
    x0[idx] = loadw(emb, (size_t)tok * (2 * F_) + f, isbf);
    x1[idx] = loadw(emb, (size_t)tok * (2 * F_) + F_ + f, isbf);
}

// out[o,s] (+)= sum_c w[woff + o*C + c] * x[c,s]; 64x64 tile, 4x4/thread
__global__ __launch_bounds__(256)
void conv1x1_kernel(float* __restrict__ out, const float* __restrict__ x,
                    const void* __restrict__ w, size_t woff, int O, int C,
                    int addres, const int* __restrict__ flag)
{
    __shared__ float wl[16][68];
    __shared__ float xl[16][68];
    const int isbf = flag[0];
    const int tid = threadIdx.x;
    const int tx = tid & 15, ty = tid >> 4;
    const int s0 = blockIdx.x * 64;
    const int o0 = blockIdx.y * 64;
    float acc[4][4] = {};
    for (int c0 = 0; c0 < C; c0 += 16) {
        if (isbf) {
            #pragma unroll
            for (int e = tid; e < 1024; e += 256) {
                int k = e & 15, o = e >> 4;
                wl[k][o] = __bfloat162float(((const bf16*)w)[woff + (size_t)(o0 + o) * C + (c0 + k)]);
            }
        } else {
            #pragma unroll
            for (int e = tid; e < 1024; e += 256) {
                int k = e & 15, o = e >> 4;
                wl[k][o] = ((const float*)w)[woff + (size_t)(o0 + o) * C + (c0 + k)];
            }
        }
        {
            int r = tid >> 4;
            int q = (tid & 15) * 4;
            *(float4*)&xl[r][q] = *(const float4*)(x + (size_t)(c0 + r) * S_ + (s0 + q));
        }
        __syncthreads();
        #pragma unroll
        for (int k = 0; k < 16; ++k) {
            float4 av = *(const float4*)&wl[k][ty * 4];
            float4 bv = *(const float4*)&xl[k][tx * 4];
            #pragma unroll
            for (int i = 0; i < 4; ++i)
                #pragma unroll
                for (int j = 0; j < 4; ++j)
                    acc[i][j] += (&av.x)[i] * (&bv.x)[j];
        }
        __syncthreads();
    }
    #pragma unroll
    for (int i = 0; i < 4; ++i) {
        int o = o0 + ty * 4 + i;
        float* po = out + (size_t)o * S_ + s0 + tx * 4;
        float4 r = make_float4(acc[i][0], acc[i][1], acc[i][2], acc[i][3]);
        if (addres) {
            float4 old = *(const float4*)po;
            r.x += old.x; r.y += old.y; r.z += old.z; r.w += old.w;
        }
        *(float4*)po = r;
    }
}

// v[i,s] = cumsum_s(mish(t[i,s]))/(s+1) * mish(t[I+i,s]) + mish(t[2I+i,s])
__global__ __launch_bounds__(256)
void scan_kernel(float* __restrict__ vout, const float* __restrict__ t)
{
    const int i = blockIdx.x;
    const float* dp  = t + (size_t)i * S_;
    const float* scp = dp + (size_t)I_ * S_;
    const float* shp = dp + (size_t)(2 * I_) * S_;
    float* op = vout + (size_t)i * S_;
    const int tid = threadIdx.x;
    const int base = tid * 16;

    float md[16];
    float lsum = 0.f;
    #pragma unroll
    for (int q = 0; q < 4; ++q) {
        float4 dv = *(const float4*)(dp + base + q * 4);
        #pragma unroll
        for (int j = 0; j < 4; ++j) {
            float m = mishf((&dv.x)[j]);
            md[q * 4 + j] = m;
            lsum += m;
        }
    }
    float ssum = lsum;
    #pragma unroll
    for (int off = 1; off < 64; off <<= 1) {
        float nv = __shfl_up(ssum, off, 64);
        if ((tid & 63) >= off) ssum += nv;
    }
    __shared__ float wtot[4];
    const int wid = tid >> 6, lane = tid & 63;
    if (lane == 63) wtot[wid] = ssum;
    __syncthreads();
    float excl = ssum - lsum;
    #pragma unroll
    for (int wq = 0; wq < 3; ++wq)
        if (wq < wid) excl += wtot[wq];

    float run = excl;
    #pragma unroll
    for (int q = 0; q < 4; ++q) {
        float4 scv = *(const float4*)(scp + base + q * 4);
        float4 shv = *(const float4*)(shp + base + q * 4);
        float4 ov;
        #pragma unroll
        for (int j = 0; j < 4; ++j) {
            run += md[q * 4 + j];
            float sdiv = (float)(base + q * 4 + j + 1);
            (&ov.x)[j] = run / sdiv * mishf((&scv.x)[j]) + mishf((&shv.x)[j]);
        }
        *(float4*)(op + base + q * 4) = ov;
    }
}

// w1 [o][c][k] (k innermost, stride 7) -> wt [k][o][c] bf16 (c contiguous)
__global__ __launch_bounds__(256)
void wtrans_kernel(bf16* __restrict__ wt, const void* __restrict__ w1,
                   size_t woff, const int* __restrict__ flag)
{
    const int isbf = flag[0];
    int idx = blockIdx.x * 256 + threadIdx.x;      // over 1536*512
    int c = idx & 511, o = idx >> 9;
    const size_t base = woff + ((size_t)o * 512 + c) * 7;
    float vals[7];
    #pragma unroll
    for (int k = 0; k < 7; ++k) vals[k] = loadw(w1, base + k, isbf);
    #pragma unroll
    for (int k = 0; k < 7; ++k)
        wt[((size_t)(k * I3_ + o) << 9) + c] = __float2bfloat16(vals[k]);
}

// Vv fp32 [c][s] -> vbt bf16 [s][c]   (64x64 LDS tile transpose)
__global__ __launch_bounds__(256)
void vtrans_kernel(bf16* __restrict__ vbt, const float* __restrict__ v)
{
    __shared__ __align__(16) bf16 lt[64][72];   // [s][c], 144 B rows (16-mult)
    const int tid = threadIdx.x;
    const int s0 = blockIdx.x * 64;
    const int c0 = blockIdx.y * 64;
    #pragma unroll
    for (int p = 0; p < 4; ++p) {
        int c = p * 16 + (tid >> 4);
        int sc = (tid & 15) * 4;
        float4 f = *(const float4*)(v + (size_t)(c0 + c) * S_ + s0 + sc);
        #pragma unroll
        for (int j = 0; j < 4; ++j)
            lt[sc + j][c] = __float2bfloat16((&f.x)[j]);
    }
    __syncthreads();
    #pragma unroll
    for (int p = 0; p < 2; ++p) {
        int ch = p * 256 + tid;
        int r = ch >> 3, g = ch & 7;
        *(bf16x8*)(vbt + ((size_t)(s0 + r) << 9) + c0 + g * 8) =
            *(const bf16x8*)&lt[r][g * 8];
    }
}

// MFMA causal conv: out[o,s] = sum_{c,k} wt[k][o][c] * vbt[s-6+k][c]
// block 64o x 128s (128 thr = 2 waves over s-halves), wave 64o x 64s = 4x4
// 16x16x32 frags. LDS pad 40 (80 B rows: 16B-aligned, 2-way banks = free).
__global__ __launch_bounds__(128)
void cconv_mfma_kernel(float* __restrict__ out, const bf16* __restrict__ vbt,
                       const bf16* __restrict__ wt)
{
    __shared__ __align__(16) bf16 wa[7][64][40];   // 35840 B
    __shared__ __align__(16) bf16 vb[134][40];     // 10720 B
    const int tid = threadIdx.x;
    const int s0 = blockIdx.x * 128;
    const int o0 = blockIdx.y * 64;
    const int wv  = tid >> 6;          // wave: s-half
    const int lane = tid & 63;
    const int l16 = lane & 15, q = lane >> 4;

    f32x4 acc[4][4];
    #pragma unroll
    for (int i = 0; i < 4; ++i)
        #pragma unroll
        for (int j = 0; j < 4; ++j)
            #pragma unroll
            for (int r = 0; r < 4; ++r) acc[i][j][r] = 0.f;

    for (int c0 = 0; c0 < I_; c0 += 32) {
        __syncthreads();
        // stage A: 7k x 64o x 32c  (1792 x 16B chunks)
        for (int ch = tid; ch < 1792; ch += 128) {
            int c8 = ch & 3;
            int o  = (ch >> 2) & 63;
            int k  = ch >> 8;
            *(bf16x8*)&wa[k][o][c8 * 8] =
                *(const bf16x8*)(wt + ((size_t)(k * I3_ + o0 + o) << 9) + c0 + c8 * 8);
        }
        // stage B: 134 rows (s0-6 .. s0+127) x 32c
        for (int ch = tid; ch < 536; ch += 128) {
            int c8 = ch & 3;
            int r  = ch >> 2;
            int s  = s0 - 6 + r;
            bf16x8 val;
            if (s >= 0) {
                val = *(const bf16x8*)(vbt + ((size_t)s << 9) + c0 + c8 * 8);
            } else {
                #pragma unroll
                for (int j = 0; j < 8; ++j) val[j] = (__bf16)0.0f;
            }
            *(bf16x8*)&vb[r][c8 * 8] = val;
        }
        __syncthreads();
        #pragma unroll
        for (int k = 0; k < 7; ++k) {
            bf16x8 af[4], bfr[4];
            #pragma unroll
            for (int i = 0; i < 4; ++i)
                af[i] = *(const bf16x8*)&wa[k][i * 16 + l16][q * 8];
            #pragma unroll
            for (int j = 0; j < 4; ++j)
                bfr[j] = *(const bf16x8*)&vb[wv * 64 + j * 16 + l16 + k][q * 8];
            #pragma unroll
            for (int i = 0; i < 4; ++i)
                #pragma unroll
                for (int j = 0; j < 4; ++j)
                    acc[i][j] = __builtin_amdgcn_mfma_f32_16x16x32_bf16(
                        af[i], bfr[j], acc[i][j], 0, 0, 0);
        }
    }
    // epilogue: C/D layout col=lane&15 (s), row=q*4+reg (o)
    #pragma unroll
    for (int i = 0; i < 4; ++i)
        #pragma unroll
        for (int j = 0; j < 4; ++j) {
            int sg = s0 + wv * 64 + j * 16 + l16;
            #pragma unroll
            for (int r = 0; r < 4; ++r) {
                int og = o0 + i * 16 + q * 4 + r;
                out[(size_t)og * S_ + sg] = acc[i][j][r];
            }
        }
}

__global__ __launch_bounds__(256)
void final_kernel(void* __restrict__ out, const float* __restrict__ x0,
                  const float* __restrict__ x1, const void* __restrict__ ow,
                  const void* __restrict__ ob, const int* __restrict__ flag)
{
    __shared__ float wl[16][68];
    __shared__ float xl[16][68];
    const int isbf = flag[0];
    const int tid = threadIdx.x;
    const int tx = tid & 15, ty = tid >> 4;
    const int s0 = blockIdx.x * 64;
    const int o0 = blockIdx.y * 64;
    const int b  = blockIdx.z;
    float acc[4][4] = {};
    for (int c0 = 0; c0 < 2 * F_; c0 += 16) {
        if (isbf) {
            #pragma unroll
            for (int e = tid; e < 1024; e += 256) {
                int k = e & 15, o = e >> 4;
                wl[k][o] = __bfloat162float(((const bf16*)ow)[(size_t)(o0 + o) * (2 * F_) + (c0 + k)]);
            }
        } else {
            #pragma unroll
            for (int e = tid; e < 1024; e += 256) {
                int k = e & 15, o = e >> 4;
                wl[k][o] = ((const float*)ow)[(size_t)(o0 + o) * (2 * F_) + (c0 + k)];
            }
        }
        {
            int r = tid >> 4;
            int q = (tid & 15) * 4;
            int cr = c0 + r;
            const float* src = (cr < F_) ? (x0 + ((size_t)b * F_ + cr) * S_)
                                         : (x1 + ((size_t)b * F_ + (cr - F_)) * S_);
            *(float4*)&xl[r][q] = *(const float4*)(src + s0 + q);
        }
        __syncthreads();
        #pragma unroll
        for (int k = 0; k < 16; ++k) {
            float4 av = *(const float4*)&wl[k][ty * 4];
            float4 bv = *(const float4*)&xl[k][tx * 4];
            #pragma unroll
            for (int i = 0; i < 4; ++i)
                #pragma unroll
                for (int j = 0; j < 4; ++j)
                    acc[i][j] += (&av.x)[i] * (&bv.x)[j];
        }
        __syncthreads();
    }
    #pragma unroll
    for (int i = 0; i < 4; ++i) {
        int o = o0 + ty * 4 + i;
        float bias = loadw(ob, o, isbf);
        size_t outoff = ((size_t)b * V_ + o) * S_ + s0 + tx * 4;
        if (isbf) {
            bf16* po = (bf16*)out + outoff;
            #pragma unroll
            for (int j = 0; j < 4; ++j)
                po[j] = __float2bfloat16(acc[i][j] + bias);
        } else {
            float* po = (float*)out + outoff;
            *(float4*)po = make_float4(acc[i][0] + bias, acc[i][1] + bias,
                                       acc[i][2] + bias, acc[i][3] + bias);
        }
    }
}

extern "C" void kernel_launch(void* const* d_in, const int* in_sizes, int n_in,
                              void* d_out, int out_size, void* d_ws, size_t ws_size,
                              hipStream_t stream)
{
    const int*  inp  = (const int*)d_in[0];
    const void* emb  = d_in[1];
    const void* w0   = d_in[2];
    const void* w1   = d_in[3];
    const void* w2   = d_in[4];
    const void* outw = d_in[5];
    const void* outb = d_in[6];

    // ws: flag(256B) + fp32 {A[B,F,S], Bb[B,F,S], T[3I,S], Vv[I,S]} (100.66 MB)
    //     + bf16 {wt[7,1536,512] 11.0 MB, vbt[4096,512] 4.2 MB}  => 115.9 MB
    const size_t NX = (size_t)B_ * F_ * S_;
    const size_t NT = (size_t)I3_ * S_;
    const size_t NV = (size_t)I_ * S_;
    int*   flag = (int*)d_ws;
    float* A  = (float*)d_ws + 64;
    float* Bb = A + NX;
    float* T  = Bb + NX;
    float* Vv = T + NT;
    bf16*  wt  = (bf16*)(Vv + NV);
    bf16*  vbt = wt + (size_t)K_ * I3_ * I_;

    detect_kernel<<<1, 256, 0, stream>>>(flag, (const unsigned short*)emb);
    embed_kernel<<<dim3((unsigned)(NX / 256)), 256, 0, stream>>>(A, Bb, inp, emb, flag);

    int swap = 0;   // tracks x0/x1 lane identity (same for all b)
    for (int d = 0; d < D_; ++d) {
        wtrans_kernel<<<dim3(I3_ * I_ / 256), 256, 0, stream>>>(
            wt, w1, (size_t)d * I3_ * I_ * K_, flag);
        for (int b = 0; b < B_; ++b) {
            float* x0 = (swap ? Bb : A) + (size_t)b * F_ * S_;
            float* x1 = (swap ? A : Bb) + (size_t)b * F_ * S_;
            conv1x1_kernel<<<dim3(S_ / 64, I3_ / 64), 256, 0, stream>>>(
                T, x1, w0, (size_t)d * I3_ * F_, I3_, F_, 0, flag);
            scan_kernel<<<dim3(I_), 256, 0, stream>>>(Vv, T);
            vtrans_kernel<<<dim3(S_ / 64, I_ / 64), 256, 0, stream>>>(vbt, Vv);
            cconv_mfma_kernel<<<dim3(S_ / 128, I3_ / 64), 128, 0, stream>>>(T, vbt, wt);
            scan_kernel<<<dim3(I_), 256, 0, stream>>>(Vv, T);
            conv1x1_kernel<<<dim3(S_ / 64, F_ / 64), 256, 0, stream>>>(
                x0, Vv, w2, (size_t)d * F_ * I_, F_, I_, 1, flag);
        }
        swap ^= 1;
    }
    // D even -> x0 lane is A, x1 lane is Bb
    final_kernel<<<dim3(S_ / 64, V_ / 64, B_), 256, 0, stream>>>(d_out, A, Bb, outw, outb, flag);
    (void)in_sizes; (void)n_in; (void)out_size; (void)ws_size;
}

// Round 5
// 7580.818 us; speedup vs baseline: 3.7026x; 1.1534x over previous
//
#include <hip/hip_runtime.h>
#include <hip/hip_bf16.h>

#define B_ 8
#define S_ 4096
#define F_ 256
#define I_ 512
#define D_ 4
#define K_ 7
#define V_ 256
#define I3_ 1536

using bf16 = __hip_bfloat16;
typedef __bf16 bf16x8 __attribute__((ext_vector_type(8)));
typedef float  f32x4  __attribute__((ext_vector_type(4)));

__device__ __forceinline__ float mishf(float x) {
    float sp = fmaxf(x, 0.0f) + log1pf(expf(-fabsf(x)));
    return x * tanhf(sp);
}

__device__ __forceinline__ float loadw(const void* p, size_t i, int isbf) {
    return isbf ? __bfloat162float(((const bf16*)p)[i]) : ((const float*)p)[i];
}

// bf16 buffers of small weights never show bf16-exponent>=132 (|x|>=32);
// fp32 buffers read as uint16 do (random mantissa bits in low halves).
__global__ __launch_bounds__(256)
void detect_kernel(int* __restrict__ flag, const unsigned short* __restrict__ p)
{
    __shared__ int sh[256];
    int cnt = 0;
    for (int j = threadIdx.x; j < 16384; j += 256) {
        unsigned int e = (p[j] >> 7) & 0xffu;
        if (e >= 132u) cnt++;
    }
    sh[threadIdx.x] = cnt;
    __syncthreads();
    for (int s = 128; s > 0; s >>= 1) {
        if ((int)threadIdx.x < s) sh[threadIdx.x] += sh[threadIdx.x + s];
        __syncthreads();
    }
    if (threadIdx.x == 0) flag[0] = (sh[0] == 0) ? 1 : 0;   // 1 => bf16 inputs
}

__global__ __launch_bounds__(256)
void embed_kernel(float* __restrict__ x0, float* __restrict__ x1,
                  const int* __restrict__ inp, const void* __restrict__ emb,
                  const int* __restrict__ flag)
{
    const int isbf = flag[0];
    size_t idx = (size_t)blockIdx.x * 256 + threadIdx.x;   // over B*F*S
    int s = (int)(idx % S_);
    int f = (int)((idx / S_) % F_);
    int b = (int)(idx / ((size_t)S_ * F_));
    int tok = inp[b * S_ + s];
    x0[idx] = loadw(emb, (size_t)tok * (2 * F_) + f, isbf);
    x1[idx] = loadw(emb, (size_t)tok * (2 * F_) + F_ + f, isbf);
}

// generic dtype-cast copy: dst[i] = (bf16)src[soff + i]
__global__ __launch_bounds__(256)
void cvt_kernel(bf16* __restrict__ dst, const void* __restrict__ src,
                size_t soff, int n, const int* __restrict__ flag)
{
    const int isbf = flag[0];
    int i = blockIdx.x * 256 + threadIdx.x;
    if (i < n) dst[i] = __float2bfloat16(loadw(src, soff + i, isbf));
}

// v[i,s] = cumsum_s(mish(t[i,s]))/(s+1) * mish(t[I+i,s]) + mish(t[2I+i,s])
__global__ __launch_bounds__(256)
void scan_kernel(float* __restrict__ vout, const float* __restrict__ t)
{
    const int i = blockIdx.x;
    const float* dp  = t + (size_t)i * S_;
    const float* scp = dp + (size_t)I_ * S_;
    const float* shp = dp + (size_t)(2 * I_) * S_;
    float* op = vout + (size_t)i * S_;
    const int tid = threadIdx.x;
    const int base = tid * 16;

    float md[16];
    float lsum = 0.f;
    #pragma unroll
    for (int q = 0; q < 4; ++q) {
        float4 dv = *(const float4*)(dp + base + q * 4);
        #pragma unroll
        for (int j = 0; j < 4; ++j) {
            float m = mishf((&dv.x)[j]);
            md[q * 4 + j] = m;
            lsum += m;
        }
    }
    float ssum = lsum;
    #pragma unroll
    for (int off = 1; off < 64; off <<= 1) {
        float nv = __shfl_up(ssum, off, 64);
        if ((tid & 63) >= off) ssum += nv;
    }
    __shared__ float wtot[4];
    const int wid = tid >> 6, lane = tid & 63;
    if (lane == 63) wtot[wid] = ssum;
    __syncthreads();
    float excl = ssum - lsum;
    #pragma unroll
    for (int wq = 0; wq < 3; ++wq)
        if (wq < wid) excl += wtot[wq];

    float run = excl;
    #pragma unroll
    for (int q = 0; q < 4; ++q) {
        float4 scv = *(const float4*)(scp + base + q * 4);
        float4 shv = *(const float4*)(shp + base + q * 4);
        float4 ov;
        #pragma unroll
        for (int j = 0; j < 4; ++j) {
            run += md[q * 4 + j];
            float sdiv = (float)(base + q * 4 + j + 1);
            (&ov.x)[j] = run / sdiv * mishf((&scv.x)[j]) + mishf((&shv.x)[j]);
        }
        *(float4*)(op + base + q * 4) = ov;
    }
}

// w1 [o][c][k] (k innermost, stride 7) -> wt [k][o][c] bf16 (c contiguous)
__global__ __launch_bounds__(256)
void wtrans_kernel(bf16* __restrict__ wt, const void* __restrict__ w1,
                   size_t woff, const int* __restrict__ flag)
{
    const int isbf = flag[0];
    int idx = blockIdx.x * 256 + threadIdx.x;      // over 1536*512
    int c = idx & 511, o = idx >> 9;
    const size_t base = woff + ((size_t)o * 512 + c) * 7;
    float vals[7];
    #pragma unroll
    for (int k = 0; k < 7; ++k) vals[k] = loadw(w1, base + k, isbf);
    #pragma unroll
    for (int k = 0; k < 7; ++k)
        wt[((size_t)(k * I3_ + o) << 9) + c] = __float2bfloat16(vals[k]);
}

// src fp32 [C][S] -> dst bf16 [S][C]   (64x64 LDS tile transpose)
__global__ __launch_bounds__(256)
void trans_kernel(bf16* __restrict__ dst, const float* __restrict__ src, int C)
{
    __shared__ __align__(16) bf16 lt[64][72];
    const int tid = threadIdx.x;
    const int s0 = blockIdx.x * 64;
    const int c0 = blockIdx.y * 64;
    #pragma unroll
    for (int p = 0; p < 4; ++p) {
        int c = p * 16 + (tid >> 4);
        int sc = (tid & 15) * 4;
        float4 f = *(const float4*)(src + (size_t)(c0 + c) * S_ + s0 + sc);
        #pragma unroll
        for (int j = 0; j < 4; ++j)
            lt[sc + j][c] = __float2bfloat16((&f.x)[j]);
    }
    __syncthreads();
    #pragma unroll
    for (int p = 0; p < 2; ++p) {
        int ch = p * 256 + tid;
        int r = ch >> 3, g = ch & 7;
        *(bf16x8*)(dst + (size_t)(s0 + r) * C + c0 + g * 8) =
            *(const bf16x8*)&lt[r][g * 8];
    }
}

// MFMA GEMM: out[o,s] (+)= sum_c wb[o*C+c] * xbt[s*C+c]
// block 64o x 128s (2 waves), 4x4 16x16x32 frags per wave.
__global__ __launch_bounds__(128)
void gemm_mfma_kernel(float* __restrict__ out, const bf16* __restrict__ wb,
                      const bf16* __restrict__ xbt, int O, int C, int addres)
{
    __shared__ __align__(16) bf16 wa[64][40];    // 5.1 KB
    __shared__ __align__(16) bf16 xb[128][40];   // 10.2 KB
    const int tid = threadIdx.x;
    const int s0 = blockIdx.x * 128;
    const int o0 = blockIdx.y * 64;
    const int wv = tid >> 6;
    const int lane = tid & 63;
    const int l16 = lane & 15, q = lane >> 4;

    f32x4 acc[4][4];
    #pragma unroll
    for (int i = 0; i < 4; ++i)
        #pragma unroll
        for (int j = 0; j < 4; ++j)
            #pragma unroll
            for (int r = 0; r < 4; ++r) acc[i][j][r] = 0.f;

    for (int c0 = 0; c0 < C; c0 += 32) {
        __syncthreads();
        #pragma unroll
        for (int ch = tid; ch < 256; ch += 128) {      // A: 64o x 32c
            int c8 = ch & 3, o = ch >> 2;
            *(bf16x8*)&wa[o][c8 * 8] =
                *(const bf16x8*)(wb + (size_t)(o0 + o) * C + c0 + c8 * 8);
        }
        #pragma unroll
        for (int ch = tid; ch < 512; ch += 128) {      // B: 128s x 32c
            int c8 = ch & 3, r = ch >> 2;
            *(bf16x8*)&xb[r][c8 * 8] =
                *(const bf16x8*)(xbt + (size_t)(s0 + r) * C + c0 + c8 * 8);
        }
        __syncthreads();
        bf16x8 af[4], bfr[4];
        #pragma unroll
        for (int i = 0; i < 4; ++i)
            af[i] = *(const bf16x8*)&wa[i * 16 + l16][q * 8];
        #pragma unroll
        for (int j = 0; j < 4; ++j)
            bfr[j] = *(const bf16x8*)&xb[wv * 64 + j * 16 + l16][q * 8];
        #pragma unroll
        for (int i = 0; i < 4; ++i)
            #pragma unroll
            for (int j = 0; j < 4; ++j)
                acc[i][j] = __builtin_amdgcn_mfma_f32_16x16x32_bf16(
                    af[i], bfr[j], acc[i][j], 0, 0, 0);
    }
    #pragma unroll
    for (int i = 0; i < 4; ++i)
        #pragma unroll
        for (int j = 0; j < 4; ++j) {
            int sg = s0 + wv * 64 + j * 16 + l16;
            #pragma unroll
            for (int r = 0; r < 4; ++r) {
                int og = o0 + i * 16 + q * 4 + r;
                float v = acc[i][j][r];
                if (addres) v += out[(size_t)og * S_ + sg];
                out[(size_t)og * S_ + sg] = v;
            }
        }
}

// MFMA causal conv: out[o,s] = sum_{c,k} wt[k][o][c] * vbt[s-6+k][c]
__global__ __launch_bounds__(128)
void cconv_mfma_kernel(float* __restrict__ out, const bf16* __restrict__ vbt,
                       const bf16* __restrict__ wt)
{
    __shared__ __align__(16) bf16 wa[7][64][40];   // 35840 B
    __shared__ __align__(16) bf16 vb[134][40];     // 10720 B
    const int tid = threadIdx.x;
    const int s0 = blockIdx.x * 128;
    const int o0 = blockIdx.y * 64;
    const int wv  = tid >> 6;
    const int lane = tid & 63;
    const int l16 = lane & 15, q = lane >> 4;

    f32x4 acc[4][4];
    #pragma unroll
    for (int i = 0; i < 4; ++i)
        #pragma unroll
        for (int j = 0; j < 4; ++j)
            #pragma unroll
            for (int r = 0; r < 4; ++r) acc[i][j][r] = 0.f;

    for (int c0 = 0; c0 < I_; c0 += 32) {
        __syncthreads();
        for (int ch = tid; ch < 1792; ch += 128) {
            int c8 = ch & 3;
            int o  = (ch >> 2) & 63;
            int k  = ch >> 8;
            *(bf16x8*)&wa[k][o][c8 * 8] =
                *(const bf16x8*)(wt + ((size_t)(k * I3_ + o0 + o) << 9) + c0 + c8 * 8);
        }
        for (int ch = tid; ch < 536; ch += 128) {
            int c8 = ch & 3;
            int r  = ch >> 2;
            int s  = s0 - 6 + r;
            bf16x8 val;
            if (s >= 0) {
                val = *(const bf16x8*)(vbt + ((size_t)s << 9) + c0 + c8 * 8);
            } else {
                #pragma unroll
                for (int j = 0; j < 8; ++j) val[j] = (__bf16)0.0f;
            }
            *(bf16x8*)&vb[r][c8 * 8] = val;
        }
        __syncthreads();
        #pragma unroll
        for (int k = 0; k < 7; ++k) {
            bf16x8 af[4], bfr[4];
            #pragma unroll
            for (int i = 0; i < 4; ++i)
                af[i] = *(const bf16x8*)&wa[k][i * 16 + l16][q * 8];
            #pragma unroll
            for (int j = 0; j < 4; ++j)
                bfr[j] = *(const bf16x8*)&vb[wv * 64 + j * 16 + l16 + k][q * 8];
            #pragma unroll
            for (int i = 0; i < 4; ++i)
                #pragma unroll
                for (int j = 0; j < 4; ++j)
                    acc[i][j] = __builtin_amdgcn_mfma_f32_16x16x32_bf16(
                        af[i], bfr[j], acc[i][j], 0, 0, 0);
        }
    }
    #pragma unroll
    for (int i = 0; i < 4; ++i)
        #pragma unroll
        for (int j = 0; j < 4; ++j) {
            int sg = s0 + wv * 64 + j * 16 + l16;
            #pragma unroll
            for (int r = 0; r < 4; ++r) {
                int og = o0 + i * 16 + q * 4 + r;
                out[(size_t)og * S_ + sg] = acc[i][j][r];
            }
        }
}

__global__ __launch_bounds__(256)
void final_kernel(void* __restrict__ out, const float* __restrict__ x0,
                  const float* __restrict__ x1, const void* __restrict__ ow,
                  const void* __restrict__ ob, const int* __restrict__ flag)
{
    __shared__ float wl[16][68];
    __shared__ float xl[16][68];
    const int isbf = flag[0];
    const int tid = threadIdx.x;
    const int tx = tid & 15, ty = tid >> 4;
    const int s0 = blockIdx.x * 64;
    const int o0 = blockIdx.y * 64;
    const int b  = blockIdx.z;
    float acc[4][4] = {};
    for (int c0 = 0; c0 < 2 * F_; c0 += 16) {
        if (isbf) {
            #pragma unroll
            for (int e = tid; e < 1024; e += 256) {
                int k = e & 15, o = e >> 4;
                wl[k][o] = __bfloat162float(((const bf16*)ow)[(size_t)(o0 + o) * (2 * F_) + (c0 + k)]);
            }
        } else {
            #pragma unroll
            for (int e = tid; e < 1024; e += 256) {
                int k = e & 15, o = e >> 4;
                wl[k][o] = ((const float*)ow)[(size_t)(o0 + o) * (2 * F_) + (c0 + k)];
            }
        }
        {
            int r = tid >> 4;
            int q = (tid & 15) * 4;
            int cr = c0 + r;
            const float* src = (cr < F_) ? (x0 + ((size_t)b * F_ + cr) * S_)
                                         : (x1 + ((size_t)b * F_ + (cr - F_)) * S_);
            *(float4*)&xl[r][q] = *(const float4*)(src + s0 + q);
        }
        __syncthreads();
        #pragma unroll
        for (int k = 0; k < 16; ++k) {
            float4 av = *(const float4*)&wl[k][ty * 4];
            float4 bv = *(const float4*)&xl[k][tx * 4];
            #pragma unroll
            for (int i = 0; i < 4; ++i)
                #pragma unroll
                for (int j = 0; j < 4; ++j)
                    acc[i][j] += (&av.x)[i] * (&bv.x)[j];
        }
        __syncthreads();
    }
    #pragma unroll
    for (int i = 0; i < 4; ++i) {
        int o = o0 + ty * 4 + i;
        float bias = loadw(ob, o, isbf);
        size_t outoff = ((size_t)b * V_ + o) * S_ + s0 + tx * 4;
        if (isbf) {
            bf16* po = (bf16*)out + outoff;
            #pragma unroll
            for (int j = 0; j < 4; ++j)
                po[j] = __float2bfloat16(acc[i][j] + bias);
        } else {
            float* po = (float*)out + outoff;
            *(float4*)po = make_float4(acc[i][0] + bias, acc[i][1] + bias,
                                       acc[i][2] + bias, acc[i][3] + bias);
        }
    }
}

extern "C" void kernel_launch(void* const* d_in, const int* in_sizes, int n_in,
                              void* d_out, int out_size, void* d_ws, size_t ws_size,
                              hipStream_t stream)
{
    const int*  inp  = (const int*)d_in[0];
    const void* emb  = d_in[1];
    const void* w0   = d_in[2];
    const void* w1   = d_in[3];
    const void* w2   = d_in[4];
    const void* outw = d_in[5];
    const void* outb = d_in[6];

    // ws (~119 MB): flag(256B) + fp32 {A, Bb [B,F,S]; T [3I,S]; Vv [I,S]}
    //   + bf16 {wt [7,1536,512]; vbt [S,512]; xbt [S,256]; wb0 [1536,256]; wb2 [256,512]}
    const size_t NX = (size_t)B_ * F_ * S_;
    const size_t NT = (size_t)I3_ * S_;
    const size_t NV = (size_t)I_ * S_;
    int*   flag = (int*)d_ws;
    float* A  = (float*)d_ws + 64;
    float* Bb = A + NX;
    float* T  = Bb + NX;
    float* Vv = T + NT;
    bf16*  wt  = (bf16*)(Vv + NV);
    bf16*  vbt = wt + (size_t)K_ * I3_ * I_;
    bf16*  xbt = vbt + (size_t)S_ * I_;
    bf16*  wb0 = xbt + (size_t)S_ * F_;
    bf16*  wb2 = wb0 + (size_t)I3_ * F_;

    detect_kernel<<<1, 256, 0, stream>>>(flag, (const unsigned short*)emb);
    embed_kernel<<<dim3((unsigned)(NX / 256)), 256, 0, stream>>>(A, Bb, inp, emb, flag);

    int swap = 0;
    for (int d = 0; d < D_; ++d) {
        wtrans_kernel<<<dim3(I3_ * I_ / 256), 256, 0, stream>>>(
            wt, w1, (size_t)d * I3_ * I_ * K_, flag);
        cvt_kernel<<<dim3(I3_ * F_ / 256), 256, 0, stream>>>(
            wb0, w0, (size_t)d * I3_ * F_, I3_ * F_, flag);
        cvt_kernel<<<dim3(F_ * I_ / 256), 256, 0, stream>>>(
            wb2, w2, (size_t)d * F_ * I_, F_ * I_, flag);
        for (int b = 0; b < B_; ++b) {
            float* x0 = (swap ? Bb : A) + (size_t)b * F_ * S_;
            float* x1 = (swap ? A : Bb) + (size_t)b * F_ * S_;
            trans_kernel<<<dim3(S_ / 64, F_ / 64), 256, 0, stream>>>(xbt, x1, F_);
            gemm_mfma_kernel<<<dim3(S_ / 128, I3_ / 64), 128, 0, stream>>>(
                T, wb0, xbt, I3_, F_, 0);
            scan_kernel<<<dim3(I_), 256, 0, stream>>>(Vv, T);
            trans_kernel<<<dim3(S_ / 64, I_ / 64), 256, 0, stream>>>(vbt, Vv, I_);
            cconv_mfma_kernel<<<dim3(S_ / 128, I3_ / 64), 128, 0, stream>>>(T, vbt, wt);
            scan_kernel<<<dim3(I_), 256, 0, stream>>>(Vv, T);
            trans_kernel<<<dim3(S_ / 64, I_ / 64), 256, 0, stream>>>(vbt, Vv, I_);
            gemm_mfma_kernel<<<dim3(S_ / 128, F_ / 64), 128, 0, stream>>>(
                x0, wb2, vbt, F_, I_, 1);
        }
        swap ^= 1;
    }
    final_kernel<<<dim3(S_ / 64, V_ / 64, B_), 256, 0, stream>>>(d_out, A, Bb, outw, outb, flag);
    (void)in_sizes; (void)n_in; (void)out_size; (void)ws_size;
}

// Round 6
// 6547.562 us; speedup vs baseline: 4.2869x; 1.1578x over previous
//
#include <hip/hip_runtime.h>
#include <hip/hip_bf16.h>

#define B_ 8
#define S_ 4096
#define F_ 256
#define I_ 512
#define D_ 4
#define K_ 7
#define V_ 256
#define I3_ 1536
#define KE_ 3584   // 7*512 flattened causal-conv K

using bf16 = __hip_bfloat16;
typedef __bf16 bf16x8 __attribute__((ext_vector_type(8)));
typedef float  f32x4  __attribute__((ext_vector_type(4)));

__device__ __forceinline__ float mishf(float x) {
    float sp = fmaxf(x, 0.0f) + log1pf(expf(-fabsf(x)));
    return x * tanhf(sp);
}

__device__ __forceinline__ float loadw(const void* p, size_t i, int isbf) {
    return isbf ? __bfloat162float(((const bf16*)p)[i]) : ((const float*)p)[i];
}

// bf16 buffers of small weights never show bf16-exponent>=132 (|x|>=32);
// fp32 buffers read as uint16 do (random mantissa bits in low halves).
__global__ __launch_bounds__(256)
void detect_kernel(int* __restrict__ flag, const unsigned short* __restrict__ p)
{
    __shared__ int sh[256];
    int cnt = 0;
    for (int j = threadIdx.x; j < 16384; j += 256) {
        unsigned int e = (p[j] >> 7) & 0xffu;
        if (e >= 132u) cnt++;
    }
    sh[threadIdx.x] = cnt;
    __syncthreads();
    for (int s = 128; s > 0; s >>= 1) {
        if ((int)threadIdx.x < s) sh[threadIdx.x] += sh[threadIdx.x + s];
        __syncthreads();
    }
    if (threadIdx.x == 0) flag[0] = (sh[0] == 0) ? 1 : 0;   // 1 => bf16 inputs
}

__global__ __launch_bounds__(256)
void embed_kernel(float* __restrict__ x0, float* __restrict__ x1,
                  const int* __restrict__ inp, const void* __restrict__ emb,
                  const int* __restrict__ flag)
{
    const int isbf = flag[0];
    size_t idx = (size_t)blockIdx.x * 256 + threadIdx.x;   // over B*F*S
    int s = (int)(idx % S_);
    int f = (int)((idx / S_) % F_);
    int b = (int)(idx / ((size_t)S_ * F_));
    int tok = inp[b * S_ + s];
    x0[idx] = loadw(emb, (size_t)tok * (2 * F_) + f, isbf);
    x1[idx] = loadw(emb, (size_t)tok * (2 * F_) + F_ + f, isbf);
}

// generic dtype-cast copy: dst[i] = (bf16)src[soff + i]
__global__ __launch_bounds__(256)
void cvt_kernel(bf16* __restrict__ dst, const void* __restrict__ src,
                size_t soff, int n, const int* __restrict__ flag)
{
    const int isbf = flag[0];
    int i = blockIdx.x * 256 + threadIdx.x;
    if (i < n) dst[i] = __float2bfloat16(loadw(src, soff + i, isbf));
}

// zero rows 0..5 of vexp (positions with s-6+k < 0 are never written by
// transexp; zero once per launch, they stay zero across all iterations)
__global__ __launch_bounds__(256)
void zero6_kernel(bf16* __restrict__ vexp)
{
    int i = blockIdx.x * 256 + threadIdx.x;
    if (i < 6 * KE_) vexp[i] = __float2bfloat16(0.0f);
}

// v[i,s] = cumsum_s(mish(t[i,s]))/(s+1) * mish(t[I+i,s]) + mish(t[2I+i,s])
__global__ __launch_bounds__(256)
void scan_kernel(float* __restrict__ vout, const float* __restrict__ t)
{
    const int i = blockIdx.x;
    const float* dp  = t + (size_t)i * S_;
    const float* scp = dp + (size_t)I_ * S_;
    const float* shp = dp + (size_t)(2 * I_) * S_;
    float* op = vout + (size_t)i * S_;
    const int tid = threadIdx.x;
    const int base = tid * 16;

    float md[16];
    float lsum = 0.f;
    #pragma unroll
    for (int q = 0; q < 4; ++q) {
        float4 dv = *(const float4*)(dp + base + q * 4);
        #pragma unroll
        for (int j = 0; j < 4; ++j) {
            float m = mishf((&dv.x)[j]);
            md[q * 4 + j] = m;
            lsum += m;
        }
    }
    float ssum = lsum;
    #pragma unroll
    for (int off = 1; off < 64; off <<= 1) {
        float nv = __shfl_up(ssum, off, 64);
        if ((tid & 63) >= off) ssum += nv;
    }
    __shared__ float wtot[4];
    const int wid = tid >> 6, lane = tid & 63;
    if (lane == 63) wtot[wid] = ssum;
    __syncthreads();
    float excl = ssum - lsum;
    #pragma unroll
    for (int wq = 0; wq < 3; ++wq)
        if (wq < wid) excl += wtot[wq];

    float run = excl;
    #pragma unroll
    for (int q = 0; q < 4; ++q) {
        float4 scv = *(const float4*)(scp + base + q * 4);
        float4 shv = *(const float4*)(shp + base + q * 4);
        float4 ov;
        #pragma unroll
        for (int j = 0; j < 4; ++j) {
            run += md[q * 4 + j];
            float sdiv = (float)(base + q * 4 + j + 1);
            (&ov.x)[j] = run / sdiv * mishf((&scv.x)[j]) + mishf((&shv.x)[j]);
        }
        *(float4*)(op + base + q * 4) = ov;
    }
}

// w1 [o][c][k] (k innermost) -> wexp [o][k*512+c] bf16 (flattened-K A matrix)
__global__ __launch_bounds__(256)
void wexp_kernel(bf16* __restrict__ wexp, const void* __restrict__ w1,
                 size_t woff, const int* __restrict__ flag)
{
    const int isbf = flag[0];
    int idx = blockIdx.x * 256 + threadIdx.x;      // over 1536*512
    int c = idx & 511, o = idx >> 9;
    const size_t base = woff + ((size_t)o * 512 + c) * 7;
    float vals[7];
    #pragma unroll
    for (int k = 0; k < 7; ++k) vals[k] = loadw(w1, base + k, isbf);
    #pragma unroll
    for (int k = 0; k < 7; ++k)
        wexp[(size_t)o * KE_ + (k << 9) + c] = __float2bfloat16(vals[k]);
}

// src fp32 [C][S] -> dst bf16 [S][C]   (64x64 LDS tile transpose) — for xbt
__global__ __launch_bounds__(256)
void trans_kernel(bf16* __restrict__ dst, const float* __restrict__ src, int C)
{
    __shared__ __align__(16) bf16 lt[64][72];
    const int tid = threadIdx.x;
    const int s0 = blockIdx.x * 64;
    const int c0 = blockIdx.y * 64;
    #pragma unroll
    for (int p = 0; p < 4; ++p) {
        int c = p * 16 + (tid >> 4);
        int sc = (tid & 15) * 4;
        float4 f = *(const float4*)(src + (size_t)(c0 + c) * S_ + s0 + sc);
        #pragma unroll
        for (int j = 0; j < 4; ++j)
            lt[sc + j][c] = __float2bfloat16((&f.x)[j]);
    }
    __syncthreads();
    #pragma unroll
    for (int p = 0; p < 2; ++p) {
        int ch = p * 256 + tid;
        int r = ch >> 3, g = ch & 7;
        *(bf16x8*)(dst + (size_t)(s0 + r) * C + c0 + g * 8) =
            *(const bf16x8*)&lt[r][g * 8];
    }
}

// Vv fp32 [512][S] -> vexp bf16 [s][k*512+c] = Vv[c][s-6+k]  (7 shifted copies)
__global__ __launch_bounds__(256)
void transexp_kernel(bf16* __restrict__ vexp, const float* __restrict__ src)
{
    __shared__ __align__(16) bf16 lt[64][72];
    const int tid = threadIdx.x;
    const int s0 = blockIdx.x * 64;     // source s
    const int c0 = blockIdx.y * 64;
    #pragma unroll
    for (int p = 0; p < 4; ++p) {
        int c = p * 16 + (tid >> 4);
        int sc = (tid & 15) * 4;
        float4 f = *(const float4*)(src + (size_t)(c0 + c) * S_ + s0 + sc);
        #pragma unroll
        for (int j = 0; j < 4; ++j)
            lt[sc + j][c] = __float2bfloat16((&f.x)[j]);
    }
    __syncthreads();
    // source row r maps to dst row r+6-k at column block k*512
    #pragma unroll
    for (int p = 0; p < 14; ++p) {
        int ch = p * 256 + tid;         // 0..3583 = 7k x 64r x 8g
        int g = ch & 7, r = (ch >> 3) & 63, k = ch >> 9;
        int sd = s0 + r + 6 - k;
        if (sd < S_)
            *(bf16x8*)(vexp + (size_t)sd * KE_ + (k << 9) + c0 + g * 8) =
                *(const bf16x8*)&lt[r][g * 8];
    }
}

// GEMM: out[o,s] (+)= sum_k Aw[o*lda + k] * Bm[s*ldb + boff + k]
// 128o x 128s tile, 256 thr = 4 waves (2x2 of 64x64), BK=64, 36.9 KB LDS
__global__ __launch_bounds__(256)
void gemm128_kernel(float* __restrict__ out, const bf16* __restrict__ Aw,
                    const bf16* __restrict__ Bm, int lda, int ldb, int boff,
                    int Kdim, int addres)
{
    __shared__ __align__(16) bf16 la[128][72];
    __shared__ __align__(16) bf16 lb[128][72];
    const int tid = threadIdx.x;
    const int s0 = blockIdx.x * 128;
    const int o0 = blockIdx.y * 128;
    const int wv = tid >> 6, lane = tid & 63;
    const int wo = wv & 1, wsv = wv >> 1;
    const int l16 = lane & 15, q = lane >> 4;

    f32x4 acc[4][4];
    #pragma unroll
    for (int i = 0; i < 4; ++i)
        #pragma unroll
        for (int j = 0; j < 4; ++j)
            #pragma unroll
            for (int r = 0; r < 4; ++r) acc[i][j][r] = 0.f;

    for (int k0 = 0; k0 < Kdim; k0 += 64) {
        __syncthreads();
        #pragma unroll
        for (int p = 0; p < 4; ++p) {          // A: 128 rows x 64k
            int ch = p * 256 + tid;
            int c8 = ch & 7, o = ch >> 3;
            *(bf16x8*)&la[o][c8 * 8] =
                *(const bf16x8*)(Aw + (size_t)(o0 + o) * lda + k0 + c8 * 8);
        }
        #pragma unroll
        for (int p = 0; p < 4; ++p) {          // B: 128 rows x 64k
            int ch = p * 256 + tid;
            int c8 = ch & 7, r = ch >> 3;
            *(bf16x8*)&lb[r][c8 * 8] =
                *(const bf16x8*)(Bm + (size_t)(s0 + r) * ldb + boff + k0 + c8 * 8);
        }
        __syncthreads();
        #pragma unroll
        for (int kk = 0; kk < 64; kk += 32) {
            bf16x8 af[4], bfr[4];
            #pragma unroll
            for (int i = 0; i < 4; ++i)
                af[i] = *(const bf16x8*)&la[wo * 64 + i * 16 + l16][kk + q * 8];
            #pragma unroll
            for (int j = 0; j < 4; ++j)
                bfr[j] = *(const bf16x8*)&lb[wsv * 64 + j * 16 + l16][kk + q * 8];
            #pragma unroll
            for (int i = 0; i < 4; ++i)
                #pragma unroll
                for (int j = 0; j < 4; ++j)
                    acc[i][j] = __builtin_amdgcn_mfma_f32_16x16x32_bf16(
                        af[i], bfr[j], acc[i][j], 0, 0, 0);
        }
    }
    // C/D: col(lane&15)=s, row(q*4+reg)=o   [verified in rounds 4-5]
    #pragma unroll
    for (int i = 0; i < 4; ++i)
        #pragma unroll
        for (int j = 0; j < 4; ++j) {
            int sg = s0 + wsv * 64 + j * 16 + l16;
            #pragma unroll
            for (int r = 0; r < 4; ++r) {
                int og = o0 + wo * 64 + i * 16 + q * 4 + r;
                float v = acc[i][j][r];
                if (addres) v += out[(size_t)og * S_ + sg];
                out[(size_t)og * S_ + sg] = v;
            }
        }
}

__global__ __launch_bounds__(256)
void final_kernel(void* __restrict__ out, const float* __restrict__ x0,
                  const float* __restrict__ x1, const void* __restrict__ ow,
                  const void* __restrict__ ob, const int* __restrict__ flag)
{
    __shared__ float wl[16][68];
    __shared__ float xl[16][68];
    const int isbf = flag[0];
    const int tid = threadIdx.x;
    const int tx = tid & 15, ty = tid >> 4;
    const int s0 = blockIdx.x * 64;
    const int o0 = blockIdx.y * 64;
    const int b  = blockIdx.z;
    float acc[4][4] = {};
    for (int c0 = 0; c0 < 2 * F_; c0 += 16) {
        if (isbf) {
            #pragma unroll
            for (int e = tid; e < 1024; e += 256) {
                int k = e & 15, o = e >> 4;
                wl[k][o] = __bfloat162float(((const bf16*)ow)[(size_t)(o0 + o) * (2 * F_) + (c0 + k)]);
            }
        } else {
            #pragma unroll
            for (int e = tid; e < 1024; e += 256) {
                int k = e & 15, o = e >> 4;
                wl[k][o] = ((const float*)ow)[(size_t)(o0 + o) * (2 * F_) + (c0 + k)];
            }
        }
        {
            int r = tid >> 4;
            int q = (tid & 15) * 4;
            int cr = c0 + r;
            const float* src = (cr < F_) ? (x0 + ((size_t)b * F_ + cr) * S_)
                                         : (x1 + ((size_t)b * F_ + (cr - F_)) * S_);
            *(float4*)&xl[r][q] = *(const float4*)(src + s0 + q);
        }
        __syncthreads();
        #pragma unroll
        for (int k = 0; k < 16; ++k) {
            float4 av = *(const float4*)&wl[k][ty * 4];
            float4 bv = *(const float4*)&xl[k][tx * 4];
            #pragma unroll
            for (int i = 0; i < 4; ++i)
                #pragma unroll
                for (int j = 0; j < 4; ++j)
                    acc[i][j] += (&av.x)[i] * (&bv.x)[j];
        }
        __syncthreads();
    }
    #pragma unroll
    for (int i = 0; i < 4; ++i) {
        int o = o0 + ty * 4 + i;
        float bias = loadw(ob, o, isbf);
        size_t outoff = ((size_t)b * V_ + o) * S_ + s0 + tx * 4;
        if (isbf) {
            bf16* po = (bf16*)out + outoff;
            #pragma unroll
            for (int j = 0; j < 4; ++j)
                po[j] = __float2bfloat16(acc[i][j] + bias);
        } else {
            float* po = (float*)out + outoff;
            *(float4*)po = make_float4(acc[i][0] + bias, acc[i][1] + bias,
                                       acc[i][2] + bias, acc[i][3] + bias);
        }
    }
}

extern "C" void kernel_launch(void* const* d_in, const int* in_sizes, int n_in,
                              void* d_out, int out_size, void* d_ws, size_t ws_size,
                              hipStream_t stream)
{
    const int*  inp  = (const int*)d_in[0];
    const void* emb  = d_in[1];
    const void* w0   = d_in[2];
    const void* w1   = d_in[3];
    const void* w2   = d_in[4];
    const void* outw = d_in[5];
    const void* outb = d_in[6];

    // ws (~144 MB): flag(256B) + fp32 {A, Bb [B,F,S]; T [3I,S]; Vv [I,S]}
    //   + bf16 {wexp [1536,3584]; vexp [4096,3584]; xbt [S,256]; wb0; wb2}
    const size_t NX = (size_t)B_ * F_ * S_;
    const size_t NT = (size_t)I3_ * S_;
    const size_t NV = (size_t)I_ * S_;
    int*   flag = (int*)d_ws;
    float* A  = (float*)d_ws + 64;
    float* Bb = A + NX;
    float* T  = Bb + NX;
    float* Vv = T + NT;
    bf16*  wexp = (bf16*)(Vv + NV);
    bf16*  vexp = wexp + (size_t)I3_ * KE_;
    bf16*  xbt  = vexp + (size_t)S_ * KE_;
    bf16*  wb0  = xbt + (size_t)S_ * F_;
    bf16*  wb2  = wb0 + (size_t)I3_ * F_;

    detect_kernel<<<1, 256, 0, stream>>>(flag, (const unsigned short*)emb);
    embed_kernel<<<dim3((unsigned)(NX / 256)), 256, 0, stream>>>(A, Bb, inp, emb, flag);
    zero6_kernel<<<dim3((6 * KE_ + 255) / 256), 256, 0, stream>>>(vexp);

    int swap = 0;
    for (int d = 0; d < D_; ++d) {
        wexp_kernel<<<dim3(I3_ * I_ / 256), 256, 0, stream>>>(
            wexp, w1, (size_t)d * I3_ * I_ * K_, flag);
        cvt_kernel<<<dim3(I3_ * F_ / 256), 256, 0, stream>>>(
            wb0, w0, (size_t)d * I3_ * F_, I3_ * F_, flag);
        cvt_kernel<<<dim3(F_ * I_ / 256), 256, 0, stream>>>(
            wb2, w2, (size_t)d * F_ * I_, F_ * I_, flag);
        for (int b = 0; b < B_; ++b) {
            float* x0 = (swap ? Bb : A) + (size_t)b * F_ * S_;
            float* x1 = (swap ? A : Bb) + (size_t)b * F_ * S_;
            trans_kernel<<<dim3(S_ / 64, F_ / 64), 256, 0, stream>>>(xbt, x1, F_);
            gemm128_kernel<<<dim3(S_ / 128, I3_ / 128), 256, 0, stream>>>(
                T, wb0, xbt, F_, F_, 0, F_, 0);
            scan_kernel<<<dim3(I_), 256, 0, stream>>>(Vv, T);
            transexp_kernel<<<dim3(S_ / 64, I_ / 64), 256, 0, stream>>>(vexp, Vv);
            gemm128_kernel<<<dim3(S_ / 128, I3_ / 128), 256, 0, stream>>>(
                T, wexp, vexp, KE_, KE_, 0, KE_, 0);
            scan_kernel<<<dim3(I_), 256, 0, stream>>>(Vv, T);
            transexp_kernel<<<dim3(S_ / 64, I_ / 64), 256, 0, stream>>>(vexp, Vv);
            // v[s][c] == vexp[s][6*512 + c]  -> gemm2 reads with boff=3072
            gemm128_kernel<<<dim3(S_ / 128, F_ / 128), 256, 0, stream>>>(
                x0, wb2, vexp, I_, KE_, 6 * 512, I_, 1);
            float* t0 = x0; (void)t0;
        }
        swap ^= 1;
    }
    final_kernel<<<dim3(S_ / 64, V_ / 64, B_), 256, 0, stream>>>(d_out, A, Bb, outw, outb, flag);
    (void)in_sizes; (void)n_in; (void)out_size; (void)ws_size;
}

// Round 7
// 5063.850 us; speedup vs baseline: 5.5429x; 1.2930x over previous
//
#include <hip/hip_runtime.h>
#include <hip/hip_bf16.h>

#define B_ 8
#define S_ 4096
#define F_ 256
#define I_ 512
#define D_ 4
#define K_ 7
#define V_ 256
#define I3_ 1536
#define KE_ 3584           // 7*512 flattened causal-conv K
#define VR_ (S_ + 8)       // vbt rows: 6 zero-pad + 4096 + 2 slack

using bf16 = __hip_bfloat16;
typedef __bf16 bf16x8 __attribute__((ext_vector_type(8)));
typedef float  f32x4  __attribute__((ext_vector_type(4)));

#define LDS_PTR(p) ((__attribute__((address_space(3))) void*)(p))
#define GLB_PTR(p) ((const __attribute__((address_space(1))) void*)(p))

__device__ __forceinline__ float mishf(float x) {
    float sp = fmaxf(x, 0.0f) + log1pf(expf(-fabsf(x)));
    return x * tanhf(sp);
}

__device__ __forceinline__ float loadw(const void* p, size_t i, int isbf) {
    return isbf ? __bfloat162float(((const bf16*)p)[i]) : ((const float*)p)[i];
}

// bf16 buffers of small weights never show bf16-exponent>=132 (|x|>=32);
// fp32 buffers read as uint16 do (random mantissa bits in low halves).
__global__ __launch_bounds__(256)
void detect_kernel(int* __restrict__ flag, const unsigned short* __restrict__ p)
{
    __shared__ int sh[256];
    int cnt = 0;
    for (int j = threadIdx.x; j < 16384; j += 256) {
        unsigned int e = (p[j] >> 7) & 0xffu;
        if (e >= 132u) cnt++;
    }
    sh[threadIdx.x] = cnt;
    __syncthreads();
    for (int s = 128; s > 0; s >>= 1) {
        if ((int)threadIdx.x < s) sh[threadIdx.x] += sh[threadIdx.x + s];
        __syncthreads();
    }
    if (threadIdx.x == 0) flag[0] = (sh[0] == 0) ? 1 : 0;   // 1 => bf16 inputs
}

__global__ __launch_bounds__(256)
void embed_kernel(float* __restrict__ x0, float* __restrict__ x1,
                  const int* __restrict__ inp, const void* __restrict__ emb,
                  const int* __restrict__ flag)
{
    const int isbf = flag[0];
    size_t idx = (size_t)blockIdx.x * 256 + threadIdx.x;   // over B*F*S
    int s = (int)(idx % S_);
    int f = (int)((idx / S_) % F_);
    int b = (int)(idx / ((size_t)S_ * F_));
    int tok = inp[b * S_ + s];
    x0[idx] = loadw(emb, (size_t)tok * (2 * F_) + f, isbf);
    x1[idx] = loadw(emb, (size_t)tok * (2 * F_) + F_ + f, isbf);
}

// generic dtype-cast copy: dst[i] = (bf16)src[soff + i]
__global__ __launch_bounds__(256)
void cvt_kernel(bf16* __restrict__ dst, const void* __restrict__ src,
                size_t soff, int n, const int* __restrict__ flag)
{
    const int isbf = flag[0];
    int i = blockIdx.x * 256 + threadIdx.x;
    if (i < n) dst[i] = __float2bfloat16(loadw(src, soff + i, isbf));
}

// zero the 6 pad rows of both vbt slices (re-poisoned every call)
__global__ __launch_bounds__(256)
void zeropad_kernel(bf16* __restrict__ vbt)
{
    int i = blockIdx.x * 256 + threadIdx.x;
    if (i < 2 * 6 * I_) {
        int z = i / (6 * I_), off = i % (6 * I_);
        vbt[(size_t)z * VR_ * I_ + off] = __float2bfloat16(0.0f);
    }
}

// v[i,s] = cumsum_s(mish(t[i,s]))/(s+1) * mish(t[I+i,s]) + mish(t[2I+i,s])
// grid (I_, 2): blockIdx.y = z scratch slice
__global__ __launch_bounds__(256)
void scan_kernel(float* __restrict__ vout, const float* __restrict__ t)
{
    const int z = blockIdx.y;
    const int i = blockIdx.x;
    t    += (size_t)z * I3_ * S_;
    vout += (size_t)z * I_ * S_;
    const float* dp  = t + (size_t)i * S_;
    const float* scp = dp + (size_t)I_ * S_;
    const float* shp = dp + (size_t)(2 * I_) * S_;
    float* op = vout + (size_t)i * S_;
    const int tid = threadIdx.x;
    const int base = tid * 16;

    float md[16];
    float lsum = 0.f;
    #pragma unroll
    for (int q = 0; q < 4; ++q) {
        float4 dv = *(const float4*)(dp + base + q * 4);
        #pragma unroll
        for (int j = 0; j < 4; ++j) {
            float m = mishf((&dv.x)[j]);
            md[q * 4 + j] = m;
            lsum += m;
        }
    }
    float ssum = lsum;
    #pragma unroll
    for (int off = 1; off < 64; off <<= 1) {
        float nv = __shfl_up(ssum, off, 64);
        if ((tid & 63) >= off) ssum += nv;
    }
    __shared__ float wtot[4];
    const int wid = tid >> 6, lane = tid & 63;
    if (lane == 63) wtot[wid] = ssum;
    __syncthreads();
    float excl = ssum - lsum;
    #pragma unroll
    for (int wq = 0; wq < 3; ++wq)
        if (wq < wid) excl += wtot[wq];

    float run = excl;
    #pragma unroll
    for (int q = 0; q < 4; ++q) {
        float4 scv = *(const float4*)(scp + base + q * 4);
        float4 shv = *(const float4*)(shp + base + q * 4);
        float4 ov;
        #pragma unroll
        for (int j = 0; j < 4; ++j) {
            run += md[q * 4 + j];
            float sdiv = (float)(base + q * 4 + j + 1);
            (&ov.x)[j] = run / sdiv * mishf((&scv.x)[j]) + mishf((&shv.x)[j]);
        }
        *(float4*)(op + base + q * 4) = ov;
    }
}

// w1 [o][c][k] (k innermost) -> wexp [o][k*512+c] bf16 (flattened-K A matrix)
__global__ __launch_bounds__(256)
void wexp_kernel(bf16* __restrict__ wexp, const void* __restrict__ w1,
                 size_t woff, const int* __restrict__ flag)
{
    const int isbf = flag[0];
    int idx = blockIdx.x * 256 + threadIdx.x;      // over 1536*512
    int c = idx & 511, o = idx >> 9;
    const size_t base = woff + ((size_t)o * 512 + c) * 7;
    float vals[7];
    #pragma unroll
    for (int k = 0; k < 7; ++k) vals[k] = loadw(w1, base + k, isbf);
    #pragma unroll
    for (int k = 0; k < 7; ++k)
        wexp[(size_t)o * KE_ + (k << 9) + c] = __float2bfloat16(vals[k]);
}

// src fp32 [C][S_] (+z*szstr) -> dst bf16 [S_][C] (+z*dzstr); 64x64 LDS tile
__global__ __launch_bounds__(256)
void trans_kernel(bf16* __restrict__ dst, size_t dzstr,
                  const float* __restrict__ src, size_t szstr, int C)
{
    __shared__ __align__(16) bf16 lt[64][72];
    const int z = blockIdx.z;
    dst += (size_t)z * dzstr;
    src += (size_t)z * szstr;
    const int tid = threadIdx.x;
    const int s0 = blockIdx.x * 64;
    const int c0 = blockIdx.y * 64;
    #pragma unroll
    for (int p = 0; p < 4; ++p) {
        int c = p * 16 + (tid >> 4);
        int sc = (tid & 15) * 4;
        float4 f = *(const float4*)(src + (size_t)(c0 + c) * S_ + s0 + sc);
        #pragma unroll
        for (int j = 0; j < 4; ++j)
            lt[sc + j][c] = __float2bfloat16((&f.x)[j]);
    }
    __syncthreads();
    #pragma unroll
    for (int p = 0; p < 2; ++p) {
        int ch = p * 256 + tid;
        int r = ch >> 3, g = ch & 7;
        *(bf16x8*)(dst + (size_t)(s0 + r) * C + c0 + g * 8) =
            *(const bf16x8*)&lt[r][g * 8];
    }
}

// GEMM with global_load_lds staging + XOR-swizzled LDS.
// out[o,s] (+)= sum_k Aw[o*lda+k] * B(s,k) where
//   conv=0: B(s,k) = Bm[s*ldb + k]
//   conv=1: B(s,k) = Bm[(s + (k>>9))*ldb + (k&511)]  (Bm = pad base, rows s-6)
// 128o x 128s tile, 256 thr = 4 waves (2x2 of 64x64), BK=64, 32 KB LDS.
__global__ __launch_bounds__(256)
void gemm128_kernel(float* __restrict__ out, size_t ozstr,
                    const bf16* __restrict__ Aw, int lda,
                    const bf16* __restrict__ Bm, size_t bzstr, int ldb,
                    int Kdim, int conv, int addres)
{
    __shared__ __align__(16) bf16 la[128][64];
    __shared__ __align__(16) bf16 lb[128][64];
    const int tid = threadIdx.x;
    const int s0 = blockIdx.x * 128;
    const int o0 = blockIdx.y * 128;
    const int z  = blockIdx.z;
    out += (size_t)z * ozstr;
    Bm  += (size_t)z * bzstr;
    const int wv = tid >> 6, lane = tid & 63;
    const int wo = wv & 1, wsv = wv >> 1;
    const int l16 = lane & 15, q = lane >> 4;
    const int lrow = lane >> 3, lslot = lane & 7;   // staging: 8 rows/wave-instr

    f32x4 acc[4][4];
    #pragma unroll
    for (int i = 0; i < 4; ++i)
        #pragma unroll
        for (int j = 0; j < 4; ++j)
            #pragma unroll
            for (int r = 0; r < 4; ++r) acc[i][j][r] = 0.f;

    for (int k0 = 0; k0 < Kdim; k0 += 64) {
        int roff = 0, bk = k0;
        if (conv) { roff = k0 >> 9; bk = k0 & 511; }
        __syncthreads();
        #pragma unroll
        for (int t = 0; t < 4; ++t) {           // A tile: 128 rows x 64k
            int rbase = wv * 32 + t * 8;
            int row = rbase + lrow;
            int chunk = lslot ^ (row & 7);      // XOR swizzle slot->chunk
            __builtin_amdgcn_global_load_lds(
                GLB_PTR(Aw + (size_t)(o0 + row) * lda + k0 + chunk * 8),
                LDS_PTR(&la[rbase][0]), 16, 0, 0);
        }
        #pragma unroll
        for (int t = 0; t < 4; ++t) {           // B tile: 128 rows x 64k
            int rbase = wv * 32 + t * 8;
            int row = rbase + lrow;
            int chunk = lslot ^ (row & 7);
            __builtin_amdgcn_global_load_lds(
                GLB_PTR(Bm + (size_t)(s0 + row + roff) * ldb + bk + chunk * 8),
                LDS_PTR(&lb[rbase][0]), 16, 0, 0);
        }
        __syncthreads();
        #pragma unroll
        for (int kk = 0; kk < 2; ++kk) {
            bf16x8 af[4], bfr[4];
            #pragma unroll
            for (int i = 0; i < 4; ++i) {
                int r = wo * 64 + i * 16 + l16;
                int c = kk * 4 + q;
                af[i] = *(const bf16x8*)&la[r][(c ^ (r & 7)) * 8];
            }
            #pragma unroll
            for (int j = 0; j < 4; ++j) {
                int r = wsv * 64 + j * 16 + l16;
                int c = kk * 4 + q;
                bfr[j] = *(const bf16x8*)&lb[r][(c ^ (r & 7)) * 8];
            }
            #pragma unroll
            for (int i = 0; i < 4; ++i)
                #pragma unroll
                for (int j = 0; j < 4; ++j)
                    acc[i][j] = __builtin_amdgcn_mfma_f32_16x16x32_bf16(
                        af[i], bfr[j], acc[i][j], 0, 0, 0);
        }
    }
    // C/D: col(lane&15)=s, row(q*4+reg)=o   [verified rounds 4-6]
    #pragma unroll
    for (int i = 0; i < 4; ++i)
        #pragma unroll
        for (int j = 0; j < 4; ++j) {
            int sg = s0 + wsv * 64 + j * 16 + l16;
            #pragma unroll
            for (int r = 0; r < 4; ++r) {
                int og = o0 + wo * 64 + i * 16 + q * 4 + r;
                float v = acc[i][j][r];
                if (addres) v += out[(size_t)og * S_ + sg];
                out[(size_t)og * S_ + sg] = v;
            }
        }
}

__global__ __launch_bounds__(256)
void final_kernel(void* __restrict__ out, const float* __restrict__ x0,
                  const float* __restrict__ x1, const void* __restrict__ ow,
                  const void* __restrict__ ob, const int* __restrict__ flag)
{
    __shared__ float wl[16][68];
    __shared__ float xl[16][68];
    const int isbf = flag[0];
    const int tid = threadIdx.x;
    const int tx = tid & 15, ty = tid >> 4;
    const int s0 = blockIdx.x * 64;
    const int o0 = blockIdx.y * 64;
    const int b  = blockIdx.z;
    float acc[4][4] = {};
    for (int c0 = 0; c0 < 2 * F_; c0 += 16) {
        if (isbf) {
            #pragma unroll
            for (int e = tid; e < 1024; e += 256) {
                int k = e & 15, o = e >> 4;
                wl[k][o] = __bfloat162float(((const bf16*)ow)[(size_t)(o0 + o) * (2 * F_) + (c0 + k)]);
            }
        } else {
            #pragma unroll
            for (int e = tid; e < 1024; e += 256) {
                int k = e & 15, o = e >> 4;
                wl[k][o] = ((const float*)ow)[(size_t)(o0 + o) * (2 * F_) + (c0 + k)];
            }
        }
        {
            int r = tid >> 4;
            int q = (tid & 15) * 4;
            int cr = c0 + r;
            const float* src = (cr < F_) ? (x0 + ((size_t)b * F_ + cr) * S_)
                                         : (x1 + ((size_t)b * F_ + (cr - F_)) * S_);
            *(float4*)&xl[r][q] = *(const float4*)(src + s0 + q);
        }
        __syncthreads();
        #pragma unroll
        for (int k = 0; k < 16; ++k) {
            float4 av = *(const float4*)&wl[k][ty * 4];
            float4 bv = *(const float4*)&xl[k][tx * 4];
            #pragma unroll
            for (int i = 0; i < 4; ++i)
                #pragma unroll
                for (int j = 0; j < 4; ++j)
                    acc[i][j] += (&av.x)[i] * (&bv.x)[j];
        }
        __syncthreads();
    }
    #pragma unroll
    for (int i = 0; i < 4; ++i) {
        int o = o0 + ty * 4 + i;
        float bias = loadw(ob, o, isbf);
        size_t outoff = ((size_t)b * V_ + o) * S_ + s0 + tx * 4;
        if (isbf) {
            bf16* po = (bf16*)out + outoff;
            #pragma unroll
            for (int j = 0; j < 4; ++j)
                po[j] = __float2bfloat16(acc[i][j] + bias);
        } else {
            float* po = (float*)out + outoff;
            *(float4*)po = make_float4(acc[i][0] + bias, acc[i][1] + bias,
                                       acc[i][2] + bias, acc[i][3] + bias);
        }
    }
}

extern "C" void kernel_launch(void* const* d_in, const int* in_sizes, int n_in,
                              void* d_out, int out_size, void* d_ws, size_t ws_size,
                              hipStream_t stream)
{
    const int*  inp  = (const int*)d_in[0];
    const void* emb  = d_in[1];
    const void* w0   = d_in[2];
    const void* w1   = d_in[3];
    const void* w2   = d_in[4];
    const void* outw = d_in[5];
    const void* outb = d_in[6];

    // ws (~159 MB): flag + fp32 {A, Bb [B,F,S]; T[2][3I,S]; Vv[2][I,S]}
    //   + bf16 {wexp [1536,3584]; vbt[2][VR_,512]; xbt[2][S,256]; wb0; wb2}
    const size_t NX = (size_t)B_ * F_ * S_;
    const size_t NT = (size_t)I3_ * S_;
    const size_t NV = (size_t)I_ * S_;
    const size_t VSTR = (size_t)VR_ * I_;     // vbt z-stride (elements)
    int*   flag = (int*)d_ws;
    float* A  = (float*)d_ws + 64;
    float* Bb = A + NX;
    float* T  = Bb + NX;                       // 2 slices
    float* Vv = T + 2 * NT;                    // 2 slices
    bf16*  wexp = (bf16*)(Vv + 2 * NV);
    bf16*  vbt  = wexp + (size_t)I3_ * KE_;    // 2 slices, 6-row zero pad each
    bf16*  xbt  = vbt + 2 * VSTR;              // 2 slices
    bf16*  wb0  = xbt + 2 * (size_t)S_ * F_;
    bf16*  wb2  = wb0 + (size_t)I3_ * F_;

    detect_kernel<<<1, 256, 0, stream>>>(flag, (const unsigned short*)emb);
    embed_kernel<<<dim3((unsigned)(NX / 256)), 256, 0, stream>>>(A, Bb, inp, emb, flag);
    zeropad_kernel<<<dim3((2 * 6 * I_ + 255) / 256), 256, 0, stream>>>(vbt);

    int swap = 0;
    for (int d = 0; d < D_; ++d) {
        wexp_kernel<<<dim3(I3_ * I_ / 256), 256, 0, stream>>>(
            wexp, w1, (size_t)d * I3_ * I_ * K_, flag);
        cvt_kernel<<<dim3(I3_ * F_ / 256), 256, 0, stream>>>(
            wb0, w0, (size_t)d * I3_ * F_, I3_ * F_, flag);
        cvt_kernel<<<dim3(F_ * I_ / 256), 256, 0, stream>>>(
            wb2, w2, (size_t)d * F_ * I_, F_ * I_, flag);
        for (int bp = 0; bp < B_ / 2; ++bp) {
            float* x0 = (swap ? Bb : A) + (size_t)(2 * bp) * F_ * S_;
            float* x1 = (swap ? A : Bb) + (size_t)(2 * bp) * F_ * S_;
            // xbt[z] = x1(b=2bp+z)^T bf16
            trans_kernel<<<dim3(S_ / 64, F_ / 64, 2), 256, 0, stream>>>(
                xbt, (size_t)S_ * F_, x1, (size_t)F_ * S_, F_);
            // T[z] = wb0 @ xbt[z]
            gemm128_kernel<<<dim3(S_ / 128, I3_ / 128, 2), 256, 0, stream>>>(
                T, NT, wb0, F_, xbt, (size_t)S_ * F_, F_, F_, 0, 0);
            scan_kernel<<<dim3(I_, 2), 256, 0, stream>>>(Vv, T);
            // vbt[z] rows 6.. = Vv[z]^T bf16 (pad rows 0..5 stay zero)
            trans_kernel<<<dim3(S_ / 64, I_ / 64, 2), 256, 0, stream>>>(
                vbt + 6 * I_, VSTR, Vv, NV, I_);
            // T[z] = causal conv as flattened-K GEMM (conv=1)
            gemm128_kernel<<<dim3(S_ / 128, I3_ / 128, 2), 256, 0, stream>>>(
                T, NT, wexp, KE_, vbt, VSTR, I_, KE_, 1, 0);
            scan_kernel<<<dim3(I_, 2), 256, 0, stream>>>(Vv, T);
            trans_kernel<<<dim3(S_ / 64, I_ / 64, 2), 256, 0, stream>>>(
                vbt + 6 * I_, VSTR, Vv, NV, I_);
            // x0(b) += wb2 @ v[z]   (vbt data rows start at +6*I_)
            gemm128_kernel<<<dim3(S_ / 128, F_ / 128, 2), 256, 0, stream>>>(
                x0, (size_t)F_ * S_, wb2, I_, vbt + 6 * I_, VSTR, I_, I_, 0, 1);
        }
        swap ^= 1;
    }
    final_kernel<<<dim3(S_ / 64, V_ / 64, B_), 256, 0, stream>>>(d_out, A, Bb, outw, outb, flag);
    (void)in_sizes; (void)n_in; (void)out_size; (void)ws_size;
}